// Round 17
// baseline (110.015 us; speedup 1.0000x reference)
//
#include <hip/hip_runtime.h>
#include <hip/hip_fp16.h>
#include <cstdint>
#include <cstddef>

// z = soft_thresh(Toeplitz(v) @ x + W2 @ y, beta) -- complex, N=1024, M=256, B=1024
// Real embedding: C[1024][2048] = A'[1024][2560] @ B'[2560][2048] (layouts R0-R5).
// Output = Re(z) only: [1024,1024] f32 (R4 finding).
//
// R17 (R13=108us is the m97-structural plateau; the documented path past it is
// producer-consumer wave specialization -- no __syncthreads in the K-loop):
//  - 512-thr blocks: waves 0-3 consumers (R13 compute), waves 4-7 producers
//  - 4-stage LDS ring (stage = 8KB A + 8KB B, BK=64); producer p owns slot p
//  - monotonic LDS flags ready[4]/cons[4]; intra-block fences only (R9 lesson)
//  - producer: issue 16 loads -> spin for ring slot free -> ds_write -> fence
//    -> ready++. consumer: spin ready -> frags -> 8 MFMA -> cons++.
//  - 64 KB LDS -> 2 blocks/CU -> 16 waves/CU (2x R13 TLP)

#define K_DIM 2560
#define BETA_F 0.01f
#define EPS_F  1e-12f

typedef __attribute__((ext_vector_type(8))) _Float16 half8;
typedef __attribute__((ext_vector_type(4))) _Float16 half4;
typedef __attribute__((ext_vector_type(4))) float   floatx4;

__device__ alignas(16) _Float16 g_Ap[1024 * K_DIM];      // 5 MB
__device__ alignas(16) _Float16 g_Bt[2048 * K_DIM];      // 10 MB

// ---------------- prep (merged): build A' and B' (identical to R13) ----------
__global__ __launch_bounds__(256) void build_all(
    const float* __restrict__ v_re, const float* __restrict__ v_im,
    const float* __restrict__ W2_re, const float* __restrict__ W2_im,
    const float* __restrict__ x_re, const float* __restrict__ x_im,
    const float* __restrict__ y_re, const float* __restrict__ y_im)
{
    const int bx = blockIdx.x;
    if (bx < 1280) {
        int t = bx * 256 + threadIdx.x;
        int i  = t / 320;
        int c  = t - i * 320;
        int kp = c * 8;                        // segment-aligned
        half8 h;
        if (kp < 1024) {
#pragma unroll
            for (int j = 0; j < 8; ++j) h[j] = (_Float16)v_re[1023 + i - kp - j];
        } else if (kp < 1280) {
            const float* s = W2_re + i * 256 + (kp - 1024);
#pragma unroll
            for (int j = 0; j < 8; ++j) h[j] = (_Float16)s[j];
        } else if (kp < 2304) {
            int k2 = kp - 1280;
#pragma unroll
            for (int j = 0; j < 8; ++j) h[j] = (_Float16)v_im[1023 + i - k2 - j];
        } else {
            const float* s = W2_im + i * 256 + (kp - 2304);
#pragma unroll
            for (int j = 0; j < 8; ++j) h[j] = (_Float16)s[j];
        }
        *reinterpret_cast<half8*>(g_Ap + (size_t)i * K_DIM + kp) = h;
        return;
    }
    __shared__ float lre[32][33];
    __shared__ float lim[32][33];
    int idx = bx - 1280;                       // 0..1279
    int bk  = idx % 40;
    int by  = idx / 40;
    const float* sre = (bk < 32) ? x_re : y_re;
    const float* sim = (bk < 32) ? x_im : y_im;
    int kb   = (bk < 32) ? bk : (bk - 32);
    int koff = (bk < 32) ? 0 : 1024;
    int k0 = kb * 32;
    int n0 = by * 32;
    int tid = threadIdx.x;
    int tx = tid & 31, ty = tid >> 5;
#pragma unroll
    for (int s = 0; s < 4; ++s) {
        int kk = ty + 8 * s;
        lre[kk][tx] = sre[(size_t)(k0 + kk) * 1024 + n0 + tx];
        lim[kk][tx] = sim[(size_t)(k0 + kk) * 1024 + n0 + tx];
    }
    __syncthreads();
    int lane_n = tid >> 3;
    int kq     = (tid & 7) * 4;
    half4 hre, him, hmim;
#pragma unroll
    for (int j = 0; j < 4; ++j) {
        float re = lre[kq + j][lane_n];
        float im = lim[kq + j][lane_n];
        hre[j]  = (_Float16)re;
        him[j]  = (_Float16)im;
        hmim[j] = (_Float16)(-im);
    }
    int n = n0 + lane_n;
    size_t kk2 = (size_t)koff + k0 + kq;
    _Float16* r0 = g_Bt + (size_t)(2 * n)     * K_DIM;
    _Float16* r1 = g_Bt + (size_t)(2 * n + 1) * K_DIM;
    *reinterpret_cast<half4*>(r0 + kk2)        = hre;
    *reinterpret_cast<half4*>(r0 + kk2 + 1280) = hmim;
    *reinterpret_cast<half4*>(r1 + kk2)        = him;
    *reinterpret_cast<half4*>(r1 + kk2 + 1280) = hre;
}

// ---------------- producer-consumer GEMM + fused soft-threshold --------------
// 64x64 tile, 512 blocks x 512 thr. Ring: 4 stages x (8KB A + 8KB B), BK=64.
// NO __syncthreads in the K-loop. XOR swizzle as R5-R16 (0 conflicts).
__global__ __launch_bounds__(512, 4) void gemm_fused(float* __restrict__ out,
                                                     int out_n)
{
    __shared__ __align__(16) _Float16 As[4 * 2 * 64 * 32];  // [slot][ksub][row][32h]
    __shared__ __align__(16) _Float16 Bs[4 * 2 * 64 * 32];
    __shared__ int ready[4];   // slot s staged up to generation ready[s]
    __shared__ int cons[4];    // total consumer-wave completions on slot s

    const int tid  = threadIdx.x;
    const int lane = tid & 63;
    const int w    = tid >> 6;           // 0..7

    const int bid = blockIdx.x;          // 0..511
    const int xcd = bid & 7;
    const int t   = bid >> 3;
    const int mi0 = ((xcd & 1) * 8 + (t & 7)) * 64;       // 0..960
    const int ni0 = ((xcd >> 1) * 8 + (t >> 3)) * 64;     // 0..1984

    if (tid < 4) { ready[tid] = 0; cons[tid] = 0; }
    __syncthreads();                     // flags visible (only barrier)

    const int NIT = K_DIM / 64;          // 40 stages of work
    volatile int* vready = (volatile int*)ready;
    volatile int* vcons  = (volatile int*)cons;

    if (w >= 4) {
        // ================= producer wave: owns ring slot p ==================
        const int p = w - 4;
        // issue geometry: 8 issues per operand; issue i: ks=i>>2, r=(i&3)*16+(lane>>2), j=lane&3
        const int rI = lane >> 2;
        const int jI = lane & 3;
        char* aSlot = (char*)As + p * 8192;
        char* bSlot = (char*)Bs + p * 8192;
        for (int g = 0; g < NIT / 4; ++g) {
            const int kt = g * 4 + p;
            half8 va[8], vb[8];
#pragma unroll
            for (int i = 0; i < 8; ++i) {
                int ks = i >> 2;
                int r  = (i & 3) * 16 + rI;
                size_t koffs = (size_t)kt * 64 + ks * 32 + jI * 8;
                va[i] = *reinterpret_cast<const half8*>(
                    g_Ap + (size_t)(mi0 + r) * K_DIM + koffs);
                vb[i] = *reinterpret_cast<const half8*>(
                    g_Bt + (size_t)(ni0 + r) * K_DIM + koffs);
            }
            if (g > 0) {                 // wait: consumers drained gen g-1
                while (vcons[p] < 4 * g) { }
            }
#pragma unroll
            for (int i = 0; i < 8; ++i) {
                int ks = i >> 2;
                int r  = (i & 3) * 16 + rI;
                int jw = jI ^ (((r & 15) >> 1) & 3);
                int off = ks * 4096 + r * 64 + jw * 16;
                *reinterpret_cast<half8*>(aSlot + off) = va[i];
                *reinterpret_cast<half8*>(bSlot + off) = vb[i];
            }
            __threadfence_block();       // writes visible before flag
            if (lane == 0) vready[p] = g + 1;
        }
        return;                          // producers exit; no epilogue
    }

    // ================= consumer wave: R13 compute ===========================
    const int wm = w >> 1;
    const int wn = w & 1;
    const int rowA = lane & 15;
    const int q    = lane >> 4;
    const int coff = (q ^ ((rowA >> 1) & 3)) * 16;

    floatx4 acc[2][2];
#pragma unroll
    for (int a = 0; a < 2; ++a)
#pragma unroll
        for (int b = 0; b < 2; ++b) acc[a][b] = (floatx4)0.0f;

    for (int kt = 0; kt < NIT; ++kt) {
        const int s = kt & 3;
        const int g = kt >> 2;
        while (vready[s] < g + 1) { }    // broadcast LDS spin
        __threadfence_block();           // acquire
        const char* Ab = (const char*)As + s * 8192;
        const char* Bb = (const char*)Bs + s * 8192;
#pragma unroll
        for (int ks = 0; ks < 2; ++ks) {
            half8 af[2], bf[2];
#pragma unroll
            for (int mi = 0; mi < 2; ++mi) {
                int r = wm * 32 + mi * 16 + rowA;
                af[mi] = *reinterpret_cast<const half8*>(Ab + ks * 4096 + r * 64 + coff);
            }
#pragma unroll
            for (int ni = 0; ni < 2; ++ni) {
                int r = wn * 32 + ni * 16 + rowA;
                bf[ni] = *reinterpret_cast<const half8*>(Bb + ks * 4096 + r * 64 + coff);
            }
#pragma unroll
            for (int mi = 0; mi < 2; ++mi)
#pragma unroll
                for (int ni = 0; ni < 2; ++ni)
                    acc[mi][ni] = __builtin_amdgcn_mfma_f32_16x16x32_f16(
                        af[mi], bf[ni], acc[mi][ni], 0, 0, 0);
        }
        // ds_reads have returned (MFMA issue required their waitcnt);
        // signal slot drained for this wave.
        if (lane == 0) atomicAdd(&cons[s], 1);
    }

    // epilogue: C/D col=lane&15, row=(lane>>4)*4+reg; lane^1 = re/im partner.
    // Output = Re(z) only: even C'-columns -> out[row*1024 + col/2].
    const int colL  = lane & 15;
    const int rquad = (lane >> 4) * 4;
#pragma unroll
    for (int mi = 0; mi < 2; ++mi)
#pragma unroll
        for (int ni = 0; ni < 2; ++ni)
#pragma unroll
            for (int r = 0; r < 4; ++r) {
                float c = acc[mi][ni][r];
                float p2 = __shfl_xor(c, 1, 64);
                float mag = sqrtf(c * c + p2 * p2);
                float sc = fmaxf(mag - BETA_F, 0.0f) / fmaxf(mag, EPS_F);
                int row = mi0 + wm * 32 + mi * 16 + rquad + r;
                int col = ni0 + wn * 32 + ni * 16 + colL;   // C' col (0..2047)
                if ((col & 1) == 0) {                        // even = Re lane
                    size_t idx = (size_t)row * 1024 + (col >> 1);
                    if (idx < (size_t)out_n) out[idx] = c * sc;
                }
            }
}

// ---------------- launcher ---------------------------------------------------
extern "C" void kernel_launch(void* const* d_in, const int* in_sizes, int n_in,
                              void* d_out, int out_size, void* d_ws, size_t ws_size,
                              hipStream_t stream) {
    (void)d_ws; (void)ws_size; (void)in_sizes; (void)n_in;
    const float* v_re  = (const float*)d_in[0];
    const float* v_im  = (const float*)d_in[1];
    const float* W2_re = (const float*)d_in[2];
    const float* W2_im = (const float*)d_in[3];
    const float* x_re  = (const float*)d_in[4];
    const float* x_im  = (const float*)d_in[5];
    const float* y_re  = (const float*)d_in[6];
    const float* y_im  = (const float*)d_in[7];
    float* out = (float*)d_out;

    build_all<<<2560, 256, 0, stream>>>(v_re, v_im, W2_re, W2_im,
                                        x_re, x_im, y_re, y_im);
    gemm_fused<<<512, 512, 0, stream>>>(out, out_size);
}

// Round 18
// 106.544 us; speedup vs baseline: 1.0326x; 1.0326x over previous
//
#include <hip/hip_runtime.h>
#include <hip/hip_fp16.h>
#include <cstdint>
#include <cstddef>

// z = soft_thresh(Toeplitz(v) @ x + W2 @ y, beta) -- complex, N=1024, M=256, B=1024
// Real embedding: C[1024][2048] = A'[1024][2560] @ B'[2560][2048] (layouts R0-R5).
// Output = Re(z) only: [1024,1024] f32 (R4 finding).
//
// R18 = revert to R13 (best measured: 108.0us). Structural sweep complete:
// R13's dbuf/1-barrier/BK=128/2-deep-prefetch beat split-K (R7/8/10), DMA
// staging (R12), cooperative merge (R14), no-LDS streaming (R15), B-halving
// (R16), and producer-consumer (R17). This is the m97-structural plateau;
// beyond it requires hand-asm K-loop interleaving (hipBLASLt territory).

#define K_DIM 2560
#define BETA_F 0.01f
#define EPS_F  1e-12f

typedef __attribute__((ext_vector_type(8))) _Float16 half8;
typedef __attribute__((ext_vector_type(4))) _Float16 half4;
typedef __attribute__((ext_vector_type(4))) float   floatx4;

__device__ alignas(16) _Float16 g_Ap[1024 * K_DIM];      // 5 MB
__device__ alignas(16) _Float16 g_Bt[2048 * K_DIM];      // 10 MB

// ---------------- prep (merged): build A' and B' -----------------------------
__global__ __launch_bounds__(256) void build_all(
    const float* __restrict__ v_re, const float* __restrict__ v_im,
    const float* __restrict__ W2_re, const float* __restrict__ W2_im,
    const float* __restrict__ x_re, const float* __restrict__ x_im,
    const float* __restrict__ y_re, const float* __restrict__ y_im)
{
    const int bx = blockIdx.x;
    if (bx < 1280) {
        int t = bx * 256 + threadIdx.x;
        int i  = t / 320;
        int c  = t - i * 320;
        int kp = c * 8;                        // segment-aligned
        half8 h;
        if (kp < 1024) {
#pragma unroll
            for (int j = 0; j < 8; ++j) h[j] = (_Float16)v_re[1023 + i - kp - j];
        } else if (kp < 1280) {
            const float* s = W2_re + i * 256 + (kp - 1024);
#pragma unroll
            for (int j = 0; j < 8; ++j) h[j] = (_Float16)s[j];
        } else if (kp < 2304) {
            int k2 = kp - 1280;
#pragma unroll
            for (int j = 0; j < 8; ++j) h[j] = (_Float16)v_im[1023 + i - k2 - j];
        } else {
            const float* s = W2_im + i * 256 + (kp - 2304);
#pragma unroll
            for (int j = 0; j < 8; ++j) h[j] = (_Float16)s[j];
        }
        *reinterpret_cast<half8*>(g_Ap + (size_t)i * K_DIM + kp) = h;
        return;
    }
    __shared__ float lre[32][33];
    __shared__ float lim[32][33];
    int idx = bx - 1280;                       // 0..1279
    int bk  = idx % 40;
    int by  = idx / 40;
    const float* sre = (bk < 32) ? x_re : y_re;
    const float* sim = (bk < 32) ? x_im : y_im;
    int kb   = (bk < 32) ? bk : (bk - 32);
    int koff = (bk < 32) ? 0 : 1024;
    int k0 = kb * 32;
    int n0 = by * 32;
    int tid = threadIdx.x;
    int tx = tid & 31, ty = tid >> 5;
#pragma unroll
    for (int s = 0; s < 4; ++s) {
        int kk = ty + 8 * s;
        lre[kk][tx] = sre[(size_t)(k0 + kk) * 1024 + n0 + tx];
        lim[kk][tx] = sim[(size_t)(k0 + kk) * 1024 + n0 + tx];
    }
    __syncthreads();
    int lane_n = tid >> 3;
    int kq     = (tid & 7) * 4;
    half4 hre, him, hmim;
#pragma unroll
    for (int j = 0; j < 4; ++j) {
        float re = lre[kq + j][lane_n];
        float im = lim[kq + j][lane_n];
        hre[j]  = (_Float16)re;
        him[j]  = (_Float16)im;
        hmim[j] = (_Float16)(-im);
    }
    int n = n0 + lane_n;
    size_t kk2 = (size_t)koff + k0 + kq;
    _Float16* r0 = g_Bt + (size_t)(2 * n)     * K_DIM;
    _Float16* r1 = g_Bt + (size_t)(2 * n + 1) * K_DIM;
    *reinterpret_cast<half4*>(r0 + kk2)        = hre;
    *reinterpret_cast<half4*>(r0 + kk2 + 1280) = hmim;
    *reinterpret_cast<half4*>(r1 + kk2)        = him;
    *reinterpret_cast<half4*>(r1 + kk2 + 1280) = hre;
}

// ---------------- non-split GEMM + fused soft-threshold, BK=128 --------------
// 64x64 tile, BK=128 (4 ksub x 32k), 512 blocks (2/CU), 4 waves = 2x2 of 32x32.
// Dbuf LDS (32KB/buf, 1 barrier/iter), 2-deep register prefetch, XOR swizzle.
__global__ __launch_bounds__(256, 2) void gemm_fused(float* __restrict__ out,
                                                     int out_n)
{
    __shared__ __align__(16) _Float16 As[2 * 4 * 64 * 32];  // [buf][ksub][row][32h]
    __shared__ __align__(16) _Float16 Bs[2 * 4 * 64 * 32];  // 32 KB each

    const int tid  = threadIdx.x;
    const int lane = tid & 63;
    const int w    = tid >> 6;
    const int wm   = w >> 1;
    const int wn   = w & 1;

    const int bid = blockIdx.x;          // 0..511
    const int xcd = bid & 7;             // round-robin -> XCD; 8x8 super-tile
    const int t   = bid >> 3;            // 0..63
    const int mi0 = ((xcd & 1) * 8 + (t & 7)) * 64;       // 0..960
    const int ni0 = ((xcd >> 1) * 8 + (t >> 3)) * 64;     // 0..1984

    floatx4 acc[2][2];
#pragma unroll
    for (int a = 0; a < 2; ++a)
#pragma unroll
        for (int b = 0; b < 2; ++b) acc[a][b] = (floatx4)0.0f;

    const int rS = tid >> 2;                 // staging row 0..63
    const int jS = tid & 3;                  // 16B chunk in 64B sub-row
    const int s0 = ((rS & 15) >> 1) & 3;
    char* asW = (char*)As + rS * 64 + ((jS ^ s0) * 16);   // + buf*16384 + ks*4096
    char* bsW = (char*)Bs + rS * 64 + ((jS ^ s0) * 16);
    const _Float16* gA = g_Ap + (size_t)(mi0 + rS) * K_DIM + jS * 8;
    const _Float16* gB = g_Bt + (size_t)(ni0 + rS) * K_DIM + jS * 8;

    const int rowA = lane & 15;
    const int q    = lane >> 4;
    const int coff = (q ^ ((rowA >> 1) & 3)) * 16;

    const int NIT = K_DIM / 128;         // 20

    // 2-deep prefetch sets: set[(kt+1)&1] holds slab kt+1 during iter kt
    half8 sA[2][4], sB[2][4];

    {   // prologue: slab 0 -> LDS buf 0 (via temps); slab 1 -> set[1]
        half8 tA[4], tB[4];
#pragma unroll
        for (int ks = 0; ks < 4; ++ks) {
            tA[ks] = *reinterpret_cast<const half8*>(gA + ks * 32);
            tB[ks] = *reinterpret_cast<const half8*>(gB + ks * 32);
        }
#pragma unroll
        for (int ks = 0; ks < 4; ++ks) {
            sA[1][ks] = *reinterpret_cast<const half8*>(gA + 128 + ks * 32);
            sB[1][ks] = *reinterpret_cast<const half8*>(gB + 128 + ks * 32);
        }
#pragma unroll
        for (int ks = 0; ks < 4; ++ks) {
            *reinterpret_cast<half8*>(asW + ks * 4096) = tA[ks];
            *reinterpret_cast<half8*>(bsW + ks * 4096) = tB[ks];
        }
    }
    __syncthreads();

#pragma unroll 2
    for (int kt = 0; kt < NIT; ++kt) {
        const int cur = kt & 1;
        const int nxt = cur ^ 1;
        if (kt + 2 < NIT) {              // issue slab kt+2 into set[cur]
            const _Float16* ga = gA + (size_t)(kt + 2) * 128;
            const _Float16* gb = gB + (size_t)(kt + 2) * 128;
#pragma unroll
            for (int ks = 0; ks < 4; ++ks) {
                sA[cur][ks] = *reinterpret_cast<const half8*>(ga + ks * 32);
                sB[cur][ks] = *reinterpret_cast<const half8*>(gb + ks * 32);
            }
        }
        const char* Ab = (const char*)As + cur * 16384;
        const char* Bb = (const char*)Bs + cur * 16384;
#pragma unroll
        for (int ks = 0; ks < 4; ++ks) {
            half8 af[2], bf[2];
#pragma unroll
            for (int mi = 0; mi < 2; ++mi) {
                int r = wm * 32 + mi * 16 + rowA;
                af[mi] = *reinterpret_cast<const half8*>(Ab + ks * 4096 + r * 64 + coff);
            }
#pragma unroll
            for (int ni = 0; ni < 2; ++ni) {
                int r = wn * 32 + ni * 16 + rowA;
                bf[ni] = *reinterpret_cast<const half8*>(Bb + ks * 4096 + r * 64 + coff);
            }
#pragma unroll
            for (int mi = 0; mi < 2; ++mi)
#pragma unroll
                for (int ni = 0; ni < 2; ++ni)
                    acc[mi][ni] = __builtin_amdgcn_mfma_f32_16x16x32_f16(
                        af[mi], bf[ni], acc[mi][ni], 0, 0, 0);
        }
        if (kt + 1 < NIT) {              // store slab kt+1 (loaded >=1 iter ago)
            char* aw = asW + nxt * 16384;
            char* bw = bsW + nxt * 16384;
#pragma unroll
            for (int ks = 0; ks < 4; ++ks) {
                *reinterpret_cast<half8*>(aw + ks * 4096) = sA[nxt][ks];
                *reinterpret_cast<half8*>(bw + ks * 4096) = sB[nxt][ks];
            }
        }
        __syncthreads();                 // single barrier per iter
    }

    // epilogue: C/D col=lane&15, row=(lane>>4)*4+reg; lane^1 = re/im partner.
    // Output = Re(z) only: even C'-columns -> out[row*1024 + col/2].
    const int colL  = lane & 15;
    const int rquad = (lane >> 4) * 4;
#pragma unroll
    for (int mi = 0; mi < 2; ++mi)
#pragma unroll
        for (int ni = 0; ni < 2; ++ni)
#pragma unroll
            for (int r = 0; r < 4; ++r) {
                float c = acc[mi][ni][r];
                float p = __shfl_xor(c, 1, 64);
                float mag = sqrtf(c * c + p * p);
                float s = fmaxf(mag - BETA_F, 0.0f) / fmaxf(mag, EPS_F);
                int row = mi0 + wm * 32 + mi * 16 + rquad + r;
                int col = ni0 + wn * 32 + ni * 16 + colL;   // C' col (0..2047)
                if ((col & 1) == 0) {                        // even = Re lane
                    size_t idx = (size_t)row * 1024 + (col >> 1);
                    if (idx < (size_t)out_n) out[idx] = c * s;
                }
            }
}

// ---------------- launcher ---------------------------------------------------
extern "C" void kernel_launch(void* const* d_in, const int* in_sizes, int n_in,
                              void* d_out, int out_size, void* d_ws, size_t ws_size,
                              hipStream_t stream) {
    (void)d_ws; (void)ws_size; (void)in_sizes; (void)n_in;
    const float* v_re  = (const float*)d_in[0];
    const float* v_im  = (const float*)d_in[1];
    const float* W2_re = (const float*)d_in[2];
    const float* W2_im = (const float*)d_in[3];
    const float* x_re  = (const float*)d_in[4];
    const float* x_im  = (const float*)d_in[5];
    const float* y_re  = (const float*)d_in[6];
    const float* y_im  = (const float*)d_in[7];
    float* out = (float*)d_out;

    build_all<<<2560, 256, 0, stream>>>(v_re, v_im, W2_re, W2_im,
                                        x_re, x_im, y_re, y_im);
    gemm_fused<<<512, 256, 0, stream>>>(out, out_size);
}